// Round 3
// baseline (726.204 us; speedup 1.0000x reference)
//
#include <hip/hip_runtime.h>

#define N_ROW 512
#define N_COL 512
#define N_INT 768
#define N_SEG (N_INT - 1)
#define WAVES_PER_BLOCK 4

// One 64-lane wave per ray. Lane l handles segments {k*64+l : k=0..11}.
// t loads are coalesced; t[j+1] load hits L1.
//
// Numerics: the harness reference is numpy FLOAT32 (R2 evidence: fp64 index
// math scored WORSE, 17.25 vs 13.1 — fp64-vs-fp32 .5-boundary flips). We must
// reproduce numpy's fp32 elementwise pipeline bit-for-bit so round(rowf)
// never flips. HIP defaults to -ffp-contract=fast-honor-pragmas, which fused
// mul+add chains into FMAs in R1 (different rounding than numpy) — the
// pragma below disables contraction so every mul/add is separately rounded,
// exactly matching numpy fp32. Residual error is reduction order only (~1e-3).
__global__ __launch_bounds__(WAVES_PER_BLOCK * 64)
void ct_fwd_kernel(const float* __restrict__ image,
                   const float* __restrict__ t_sorted,
                   const float* __restrict__ M,
                   const float* __restrict__ b,
                   const float* __restrict__ src,
                   const float* __restrict__ dst,
                   float* __restrict__ out,
                   int n_ray)
{
#pragma clang fp contract(off)
    const int wave = threadIdx.x >> 6;
    const int lane = threadIdx.x & 63;
    const int ray  = blockIdx.x * WAVES_PER_BLOCK + wave;
    if (ray >= n_ray) return;

    // 2x2 inverse in fp32 (adjugate/det) — exact for identity M (LAPACK
    // sgetri on eye(2) also returns exact identity, incl. signed zeros
    // behaving identically under mul/add).
    const float m00 = M[0], m01 = M[1], m10 = M[2], m11 = M[3];
    const float det  = m00 * m11 - m01 * m10;   // contract off: sub separate
    const float rdet = 1.0f / det;
    const float i00 =  m11 * rdet;
    const float i01 = -(m01 * rdet);
    const float i10 = -(m10 * rdet);
    const float i11 =  m00 * rdet;
    const float b0 = b[0], b1 = b[1];

    const float sx  = src[2 * ray];
    const float sy  = src[2 * ray + 1];
    const float ddx = dst[2 * ray]     - sx;
    const float ddy = dst[2 * ray + 1] - sy;

    const float* __restrict__ tp = t_sorted + (size_t)ray * N_INT;

    float acc = 0.0f;
#pragma unroll
    for (int k = 0; k < (N_INT + 63) / 64; ++k) {
        const int j = k * 64 + lane;
        if (j < N_SEG) {
            const float t0 = tp[j];
            const float t1 = tp[j + 1];

            // pts = src + t*(dst-src): mul rounded, then add rounded (no FMA)
            const float px0 = t0 * ddx;
            const float py0 = t0 * ddy;
            const float px1 = t1 * ddx;
            const float py1 = t1 * ddy;
            const float x0 = sx + px0;
            const float y0 = sy + py0;
            const float x1 = sx + px1;
            const float y1 = sy + py1;

            const float ex = x1 - x0;
            const float ey = y1 - y0;
            const float ex2 = ex * ex;
            const float ey2 = ey * ey;
            const float seg = __fsqrt_rn(ex2 + ey2);  // IEEE sqrt == np.sqrt

            const float sxm = x0 + x1;
            const float sym = y0 + y1;
            const float mx = 0.5f * sxm - b0;
            const float my = 0.5f * sym - b1;

            const float r0 = i00 * mx;
            const float r1 = i01 * my;
            const float c0 = i10 * mx;
            const float c1 = i11 * my;
            const float rowf = r0 + r1;
            const float colf = c0 + c1;

            const int ri = (int)rintf(rowf);   // half-to-even == np.round
            const int ci = (int)rintf(colf);

            const bool valid = (ri >= 0) & (ri < N_ROW) & (ci >= 0) & (ci < N_COL);
            const int flat = valid ? (ri * N_COL + ci) : 0;
            const float pv = image[flat];
            acc += valid ? pv * seg : 0.0f;
        }
    }

    // wave64 reduction
#pragma unroll
    for (int off = 32; off > 0; off >>= 1)
        acc += __shfl_down(acc, off, 64);

    if (lane == 0) out[ray] = acc;
}

extern "C" void kernel_launch(void* const* d_in, const int* in_sizes, int n_in,
                              void* d_out, int out_size, void* d_ws, size_t ws_size,
                              hipStream_t stream)
{
    const float* image    = (const float*)d_in[0];
    const float* t_sorted = (const float*)d_in[1];
    const float* M        = (const float*)d_in[2];
    const float* b        = (const float*)d_in[3];
    const float* src      = (const float*)d_in[4];
    const float* dst      = (const float*)d_in[5];
    float* out = (float*)d_out;

    const int n_ray = in_sizes[4] / 2;  // src is (n_ray, 2)
    const int grid = (n_ray + WAVES_PER_BLOCK - 1) / WAVES_PER_BLOCK;
    ct_fwd_kernel<<<grid, WAVES_PER_BLOCK * 64, 0, stream>>>(
        image, t_sorted, M, b, src, dst, out, n_ray);
}

// Round 4
// 635.325 us; speedup vs baseline: 1.1430x; 1.1430x over previous
//
#include <hip/hip_runtime.h>

#define N_ROW 512
#define N_COL 512
#define N_INT 768
#define N_SEG (N_INT - 1)
#define WPB 4

// One wave per ray. Lane l owns t[c*256 + 4l .. 4l+3] for chunks c=0..2,
// loaded as three coalesced float4's (1 KB/instr, all in flight at once —
// R3 was latency-bound: 2 scalar t-loads serialized per iteration, HBM 8%,
// VALU 30%). Neighbor positions for segment endpoints come via shfl
// (register move, no rounding) so the bit-exact numpy-fp32 elementwise
// pipeline (contract OFF — FMA contraction was the R1 failure) is preserved.
__global__ __launch_bounds__(WPB * 64)
void ct_fwd_kernel(const float* __restrict__ image,
                   const float* __restrict__ t_sorted,
                   const float* __restrict__ M,
                   const float* __restrict__ b,
                   const float* __restrict__ src,
                   const float* __restrict__ dst,
                   float* __restrict__ out,
                   int n_ray)
{
#pragma clang fp contract(off)
    const int wave = threadIdx.x >> 6;
    const int lane = threadIdx.x & 63;
    const int ray  = blockIdx.x * WPB + wave;
    if (ray >= n_ray) return;

    // 2x2 inverse (adjugate/det), fp32, contract off — exact for identity M.
    const float m00 = M[0], m01 = M[1], m10 = M[2], m11 = M[3];
    const float det  = m00 * m11 - m01 * m10;
    const float rdet = 1.0f / det;
    const float i00 =  m11 * rdet;
    const float i01 = -(m01 * rdet);
    const float i10 = -(m10 * rdet);
    const float i11 =  m00 * rdet;
    const float b0 = b[0], b1 = b[1];

    const float sx  = src[2 * ray];
    const float sy  = src[2 * ray + 1];
    const float ddx = dst[2 * ray]     - sx;
    const float ddy = dst[2 * ray + 1] - sy;

    // Three independent coalesced 16B loads — max MLP on the streamed array.
    const float4* __restrict__ tp4 =
        (const float4*)(t_sorted + (size_t)ray * N_INT);
    const float4 q0 = tp4[lane];
    const float4 q1 = tp4[64 + lane];
    const float4 q2 = tp4[128 + lane];

    const float tv[12] = {q0.x, q0.y, q0.z, q0.w,
                          q1.x, q1.y, q1.z, q1.w,
                          q2.x, q2.y, q2.z, q2.w};
    float X[12], Y[12];
#pragma unroll
    for (int i = 0; i < 12; ++i) {
        const float px = tv[i] * ddx;     // mul rounded, then add rounded
        const float py = tv[i] * ddy;     // (no FMA) == numpy fp32
        X[i] = sx + px;
        Y[i] = sy + py;
    }

    float acc = 0.0f;
#pragma unroll
    for (int c = 0; c < 3; ++c) {
        // Position of t[c*256 + 4l + 4]: lane l+1's elem0 (same chunk);
        // for lane 63 it's lane 0's elem0 of chunk c+1 (c<2) or invalid (c=2).
        float nX = __shfl_down(X[4 * c], 1, 64);
        float nY = __shfl_down(Y[4 * c], 1, 64);
        if (c < 2) {
            const float bX = __shfl(X[4 * c + 4], 0, 64);
            const float bY = __shfl(Y[4 * c + 4], 0, 64);
            if (lane == 63) { nX = bX; nY = bY; }
        }
#pragma unroll
        for (int i = 0; i < 4; ++i) {
            const float x0 = X[4 * c + i];
            const float y0 = Y[4 * c + i];
            const float x1 = (i < 3) ? X[4 * c + i + 1] : nX;
            const float y1 = (i < 3) ? Y[4 * c + i + 1] : nY;
            // j = c*256 + 4*lane + i; only j == 767 is out of range.
            const bool segv = !((c == 2) & (i == 3) & (lane == 63));

            const float ex = x1 - x0;
            const float ey = y1 - y0;
            const float ex2 = ex * ex;
            const float ey2 = ey * ey;
            const float seg = __fsqrt_rn(ex2 + ey2);

            const float sxm = x0 + x1;
            const float sym = y0 + y1;
            const float mx = 0.5f * sxm - b0;
            const float my = 0.5f * sym - b1;

            const float r0 = i00 * mx;
            const float r1 = i01 * my;
            const float c0 = i10 * mx;
            const float c1 = i11 * my;
            const float rowf = r0 + r1;
            const float colf = c0 + c1;

            const int ri = (int)rintf(rowf);   // half-to-even == np.round
            const int ci = (int)rintf(colf);

            const bool valid = (ri >= 0) & (ri < N_ROW) &
                               (ci >= 0) & (ci < N_COL) & segv;
            const int flat = valid ? (ri * N_COL + ci) : 0;
            const float pv = image[flat];
            acc += valid ? pv * seg : 0.0f;
        }
    }

    // wave64 reduction
#pragma unroll
    for (int off = 32; off > 0; off >>= 1)
        acc += __shfl_down(acc, off, 64);

    if (lane == 0) out[ray] = acc;
}

extern "C" void kernel_launch(void* const* d_in, const int* in_sizes, int n_in,
                              void* d_out, int out_size, void* d_ws, size_t ws_size,
                              hipStream_t stream)
{
    const float* image    = (const float*)d_in[0];
    const float* t_sorted = (const float*)d_in[1];
    const float* M        = (const float*)d_in[2];
    const float* b        = (const float*)d_in[3];
    const float* src      = (const float*)d_in[4];
    const float* dst      = (const float*)d_in[5];
    float* out = (float*)d_out;

    const int n_ray = in_sizes[4] / 2;  // src is (n_ray, 2)
    const int grid = (n_ray + WPB - 1) / WPB;
    ct_fwd_kernel<<<grid, WPB * 64, 0, stream>>>(
        image, t_sorted, M, b, src, dst, out, n_ray);
}

// Round 5
// 624.295 us; speedup vs baseline: 1.1632x; 1.0177x over previous
//
#include <hip/hip_runtime.h>

#define N_ROW 512
#define N_COL 512
#define N_INT 768
#define N_SEG (N_INT - 1)
#define WPB 4

// One wave per ray. INTERLEAVED lane->segment map: lane l, chunk c handles
// segment j = c*64 + l (c = 0..11). Rationale (R4 post-mortem): the kernel is
// gather-throughput-bound — each image gather splits into one L1/L2 line
// request per distinct 64B line across the 64 lanes. Interleaving puts
// simultaneous lanes 1.05 px apart along the ray (vs 4.2 px chunked), so a
// gather spans ~67 px instead of ~270 px -> fewer distinct lines per gather.
// All 12 t-loads (coalesced 256 B each) are issued upfront for MLP (the R3
// serialization bug). Neighbor t[j+1] comes via shfl (LDS pipe, keeps the
// TA pipe free), then x1/y1 are recomputed from t1 exactly as numpy does.
// Bit-exact numpy-fp32 elementwise pipeline: contract OFF (R1 failure was
// FMA contraction), rintf = half-to-even = np.round.
__global__ __launch_bounds__(WPB * 64)
void ct_fwd_kernel(const float* __restrict__ image,
                   const float* __restrict__ t_sorted,
                   const float* __restrict__ M,
                   const float* __restrict__ b,
                   const float* __restrict__ src,
                   const float* __restrict__ dst,
                   float* __restrict__ out,
                   int n_ray)
{
#pragma clang fp contract(off)
    const int wave = threadIdx.x >> 6;
    const int lane = threadIdx.x & 63;
    const int ray  = blockIdx.x * WPB + wave;
    if (ray >= n_ray) return;

    // 2x2 inverse (adjugate/det), fp32, contract off — exact for identity M.
    const float m00 = M[0], m01 = M[1], m10 = M[2], m11 = M[3];
    const float det  = m00 * m11 - m01 * m10;
    const float rdet = 1.0f / det;
    const float i00 =  m11 * rdet;
    const float i01 = -(m01 * rdet);
    const float i10 = -(m10 * rdet);
    const float i11 =  m00 * rdet;
    const float b0 = b[0], b1 = b[1];

    const float sx  = src[2 * ray];
    const float sy  = src[2 * ray + 1];
    const float ddx = dst[2 * ray]     - sx;
    const float ddy = dst[2 * ray + 1] - sy;

    const float* __restrict__ tp = t_sorted + (size_t)ray * N_INT;

    // 12 independent coalesced dword loads, all in flight before first use.
    float tv[12];
#pragma unroll
    for (int c = 0; c < 12; ++c)
        tv[c] = tp[c * 64 + lane];

    // t[j+1] for j = c*64+lane: lane+1 of chunk c, or lane 0 of chunk c+1.
    float tu[12];
#pragma unroll
    for (int c = 0; c < 12; ++c) {
        float u = __shfl_down(tv[c], 1, 64);
        if (c < 11) {
            const float brd = __shfl(tv[c + 1], 0, 64);
            if (lane == 63) u = brd;
        }
        tu[c] = u;
    }

    float acc = 0.0f;
#pragma unroll
    for (int c = 0; c < 12; ++c) {
        const float t0 = tv[c];
        const float t1 = tu[c];

        // pts = src + t*(dst-src): mul rounded, then add rounded (no FMA)
        const float px0 = t0 * ddx;
        const float py0 = t0 * ddy;
        const float px1 = t1 * ddx;
        const float py1 = t1 * ddy;
        const float x0 = sx + px0;
        const float y0 = sy + py0;
        const float x1 = sx + px1;
        const float y1 = sy + py1;

        const float ex = x1 - x0;
        const float ey = y1 - y0;
        const float ex2 = ex * ex;
        const float ey2 = ey * ey;
        const float seg = __fsqrt_rn(ex2 + ey2);

        const float sxm = x0 + x1;
        const float sym = y0 + y1;
        const float mx = 0.5f * sxm - b0;
        const float my = 0.5f * sym - b1;

        const float r0 = i00 * mx;
        const float r1 = i01 * my;
        const float c0 = i10 * mx;
        const float c1 = i11 * my;
        const float rowf = r0 + r1;
        const float colf = c0 + c1;

        const int ri = (int)rintf(rowf);   // half-to-even == np.round
        const int ci = (int)rintf(colf);

        // segment j = c*64 + lane; only j == 767 is out of range.
        const bool segv = !((c == 11) & (lane == 63));
        const bool valid = (ri >= 0) & (ri < N_ROW) &
                           (ci >= 0) & (ci < N_COL) & segv;
        const int flat = valid ? (ri * N_COL + ci) : 0;
        const float pv = image[flat];
        acc += valid ? pv * seg : 0.0f;
    }

    // wave64 reduction
#pragma unroll
    for (int off = 32; off > 0; off >>= 1)
        acc += __shfl_down(acc, off, 64);

    if (lane == 0) out[ray] = acc;
}

extern "C" void kernel_launch(void* const* d_in, const int* in_sizes, int n_in,
                              void* d_out, int out_size, void* d_ws, size_t ws_size,
                              hipStream_t stream)
{
    const float* image    = (const float*)d_in[0];
    const float* t_sorted = (const float*)d_in[1];
    const float* M        = (const float*)d_in[2];
    const float* b        = (const float*)d_in[3];
    const float* src      = (const float*)d_in[4];
    const float* dst      = (const float*)d_in[5];
    float* out = (float*)d_out;

    const int n_ray = in_sizes[4] / 2;  // src is (n_ray, 2)
    const int grid = (n_ray + WPB - 1) / WPB;
    ct_fwd_kernel<<<grid, WPB * 64, 0, stream>>>(
        image, t_sorted, M, b, src, dst, out, n_ray);
}